// Round 1
// baseline (1852.534 us; speedup 1.0000x reference)
//
#include <hip/hip_runtime.h>
#include <hip/hip_cooperative_groups.h>

namespace cg = cooperative_groups;

static constexpr int NB = 128;   // batches
static constexpr int NN = 512;   // agents (rows)
static constexpr int NM = 512;   // tasks (cols)
static constexpr int STRIPS = 8; // workgroups per batch
static constexpr int SW = 64;    // strip width (rows for row-passes, cols for col-passes)
static constexpr int NTHREADS = 256;
static constexpr int NITER = 5;

// 1024 workgroups x 256 threads; __launch_bounds__(256,4): 4 waves/EU -> 4 wgs/CU
// -> exactly 1024 co-resident wgs for the cooperative grid sync.
__global__ __launch_bounds__(NTHREADS, 4)
void gumbel_sinkhorn_kernel(const float* __restrict__ logits,
                            const int* __restrict__ nfree,
                            const int* __restrict__ ntask,
                            float* __restrict__ X,        // = d_out, updated in place
                            float* __restrict__ rowsum,   // [NB][NN] in ws
                            float* __restrict__ colsum)   // [NB][NM] in ws
{
    cg::grid_group grid = cg::this_grid();
    // idx = s*128 + b  =>  all strips of batch b share idx%8 == b%8 (same XCD L2)
    const int b    = blockIdx.x & (NB - 1);
    const int s    = blockIdx.x >> 7;
    const int na   = nfree[b];
    const int nt   = ntask[b];
    const int tid  = threadIdx.x;
    const int wv   = tid >> 6;
    const int lane = tid & 63;

    float* __restrict__ Xb       = X + (size_t)b * NN * NM;
    const float* __restrict__ Lb = logits + (size_t)b * NN * NM;
    float* __restrict__ rs       = rowsum + b * NN;
    float* __restrict__ cs       = colsum + b * NM;

    __shared__ float red[4][64];

    const int m0 = lane * 4;        // float4 #1 covers cols [m0, m0+4)
    const int m1 = 256 + lane * 4;  // float4 #2 covers cols [m1, m1+4)

    // ---------- P0: E0 = exp(logits) on valid region, zeros elsewhere, rowsums ----------
    // (TAU == 1, logits ~ N(0,1): max-subtraction unnecessary)
    for (int r = s * SW + wv; r < (s + 1) * SW; r += 4) {
        float4 o0 = make_float4(0.f, 0.f, 0.f, 0.f);
        float4 o1 = o0;
        if (r < na) {
            const float4 a0 = *(const float4*)(Lb + (size_t)r * NM + m0);
            const float4 a1 = *(const float4*)(Lb + (size_t)r * NM + m1);
            float v[8] = {a0.x, a0.y, a0.z, a0.w, a1.x, a1.y, a1.z, a1.w};
            float e[8];
            float sum = 0.f;
#pragma unroll
            for (int k = 0; k < 8; ++k) {
                const int m = (k < 4) ? (m0 + k) : (m1 + (k - 4));
                e[k] = (m < nt) ? __expf(v[k]) : 0.f;
                sum += e[k];
            }
            o0 = make_float4(e[0], e[1], e[2], e[3]);
            o1 = make_float4(e[4], e[5], e[6], e[7]);
#pragma unroll
            for (int off = 32; off >= 1; off >>= 1) sum += __shfl_xor(sum, off, 64);
            if (lane == 0) rs[r] = sum;
        }
        *(float4*)(Xb + (size_t)r * NM + m0) = o0;
        *(float4*)(Xb + (size_t)r * NM + m1) = o1;
    }
    grid.sync();

    for (int it = 0; it < NITER; ++it) {
        // ---------- R pass (col-oriented): X = exp(X / rowsum); colsum = sum over rows ----------
        {
            const int c = s * SW + lane;
            const bool act = (c < nt);
            float csum = 0.f;
            if (act) {
                for (int r = wv; r < na; r += 4) {
                    const float inv = 1.0f / rs[r];
                    const float e = __expf(Xb[(size_t)r * NM + c] * inv);
                    Xb[(size_t)r * NM + c] = e;
                    csum += e;
                }
            }
            red[wv][lane] = csum;
            __syncthreads();
            if (wv == 0 && act)
                cs[c] = red[0][lane] + red[1][lane] + red[2][lane] + red[3][lane];
        }
        grid.sync();

        // ---------- C pass (row-oriented): final ? out = X/colsum : X = exp(X/colsum); rowsums ----------
        {
            const bool fin = (it == NITER - 1);
            const float4 c0 = *(const float4*)(cs + m0);
            const float4 c1 = *(const float4*)(cs + m1);
            float cw[8] = {c0.x, c0.y, c0.z, c0.w, c1.x, c1.y, c1.z, c1.w};
            float inv[8];
#pragma unroll
            for (int k = 0; k < 8; ++k) {
                const int m = (k < 4) ? (m0 + k) : (m1 + (k - 4));
                inv[k] = (m < nt) ? (1.0f / cw[k]) : 0.f;  // 0 for masked cols -> result stays 0
            }
            const int rend = min(na, (s + 1) * SW);
            for (int r = s * SW + wv; r < rend; r += 4) {
                const float4 x0 = *(const float4*)(Xb + (size_t)r * NM + m0);
                const float4 x1 = *(const float4*)(Xb + (size_t)r * NM + m1);
                float xv[8] = {x0.x, x0.y, x0.z, x0.w, x1.x, x1.y, x1.z, x1.w};
                float ov[8];
                float sum = 0.f;
                if (fin) {
#pragma unroll
                    for (int k = 0; k < 8; ++k) ov[k] = xv[k] * inv[k];
                } else {
#pragma unroll
                    for (int k = 0; k < 8; ++k) {
                        const int m = (k < 4) ? (m0 + k) : (m1 + (k - 4));
                        const float e = (m < nt) ? __expf(xv[k] * inv[k]) : 0.f;
                        ov[k] = e;
                        sum += e;
                    }
                }
                *(float4*)(Xb + (size_t)r * NM + m0) = make_float4(ov[0], ov[1], ov[2], ov[3]);
                *(float4*)(Xb + (size_t)r * NM + m1) = make_float4(ov[4], ov[5], ov[6], ov[7]);
                if (!fin) {
#pragma unroll
                    for (int off = 32; off >= 1; off >>= 1) sum += __shfl_xor(sum, off, 64);
                    if (lane == 0) rs[r] = sum;
                }
            }
        }
        if (it < NITER - 1) grid.sync();
    }
}

extern "C" void kernel_launch(void* const* d_in, const int* in_sizes, int n_in,
                              void* d_out, int out_size, void* d_ws, size_t ws_size,
                              hipStream_t stream)
{
    (void)in_sizes; (void)n_in; (void)out_size; (void)ws_size;
    const float* logits = (const float*)d_in[0];
    const int* nfree    = (const int*)d_in[1];
    const int* ntask    = (const int*)d_in[2];
    float* X      = (float*)d_out;
    float* rowsum = (float*)d_ws;                 // 128*512 f32
    float* colsum = rowsum + NB * NN;             // 128*512 f32 (total 512 KB of ws)

    void* args[] = {(void*)&logits, (void*)&nfree, (void*)&ntask,
                    (void*)&X, (void*)&rowsum, (void*)&colsum};
    hipLaunchCooperativeKernel((const void*)gumbel_sinkhorn_kernel,
                               dim3(NB * STRIPS), dim3(NTHREADS),
                               args, 0, stream);
}

// Round 5
// 351.658 us; speedup vs baseline: 5.2680x; 5.2680x over previous
//
#include <hip/hip_runtime.h>

static constexpr int NB = 128;   // batches
static constexpr int NN = 512;   // agents (rows)
static constexpr int NM = 512;   // tasks (cols)
static constexpr int STRIPS = 8; // workgroups per batch
static constexpr int NTHREADS = 256;
static constexpr int NITER = 5;
static constexpr int PSZ = NB * NM * STRIPS; // floats per partial buffer (2 MB)

// Non-cooperative 6-launch schedule (stream order replaces grid.sync — ordinary
// launches can't fail co-residency validation, which silently killed rounds 2/4's
// cooperative launches when register pressure dropped occupancy below the grid).
//   K0: X = msk*exp(rowsoftmax(exp(logits)));   zero-fill invalid; col partials
//   K1 x4: colsum gather; Z=Y/colsum; Ez=msk*exp(Z); W=Ez/rowsum; Y'=msk*exp(W)
//   K2: out = Y/colsum
// blockIdx = s*128 + b -> all 8 strips of batch b on XCD b%8 (partials L2-local).
// Rows interleaved r = s + 8*wv + 32*i -> every wave gets ~na/32 valid rows.

__device__ __forceinline__ float wave_sum(float v) {
#pragma unroll
    for (int off = 32; off >= 1; off >>= 1) v += __shfl_xor(v, off, 64);
    return v;
}

__global__ __launch_bounds__(NTHREADS, 4)
void k0_init(const float* __restrict__ logits, const int* __restrict__ nfree,
             const int* __restrict__ ntask, float* __restrict__ X,
             float* __restrict__ part0)
{
    const int b = blockIdx.x & (NB - 1);
    const int s = blockIdx.x >> 7;
    const int na = nfree[b], nt = ntask[b];
    const int tid = threadIdx.x, wv = tid >> 6, lane = tid & 63;
    float* __restrict__ Xb       = X + (size_t)b * NN * NM;
    const float* __restrict__ Lb = logits + (size_t)b * NN * NM;

    __shared__ __align__(16) float red[4][NM];

    const int m0 = lane * 4, m1 = 256 + lane * 4;
    const bool a0 = (m0 < nt), a1 = (m1 < nt);
    float msk[8];
#pragma unroll
    for (int k = 0; k < 8; ++k)
        msk[k] = (((k < 4) ? m0 + k : m1 + k - 4) < nt) ? 1.f : 0.f;

    const int rstart = s + 8 * wv;
    float ca[8];
#pragma unroll
    for (int k = 0; k < 8; ++k) ca[k] = 0.f;

    int r = rstart;
    for (; r < na; r += 32) {
        float e[8];
#pragma unroll
        for (int k = 0; k < 8; ++k) e[k] = 0.f;
        if (a0) {
            const float4 x = *(const float4*)(Lb + (size_t)r * NM + m0);
            e[0] = msk[0] * __expf(x.x); e[1] = msk[1] * __expf(x.y);
            e[2] = msk[2] * __expf(x.z); e[3] = msk[3] * __expf(x.w);
        }
        if (a1) {
            const float4 x = *(const float4*)(Lb + (size_t)r * NM + m1);
            e[4] = msk[4] * __expf(x.x); e[5] = msk[5] * __expf(x.y);
            e[6] = msk[6] * __expf(x.z); e[7] = msk[7] * __expf(x.w);
        }
        const float sum = wave_sum(((e[0] + e[1]) + (e[2] + e[3])) +
                                   ((e[4] + e[5]) + (e[6] + e[7])));
        const float invr = 1.0f / sum; // >0 whenever a0|a1
        float4 o0 = make_float4(0.f, 0.f, 0.f, 0.f), o1 = o0;
        if (a0) {
            o0 = make_float4(msk[0] * __expf(e[0] * invr), msk[1] * __expf(e[1] * invr),
                             msk[2] * __expf(e[2] * invr), msk[3] * __expf(e[3] * invr));
            ca[0] += o0.x; ca[1] += o0.y; ca[2] += o0.z; ca[3] += o0.w;
        }
        if (a1) {
            o1 = make_float4(msk[4] * __expf(e[4] * invr), msk[5] * __expf(e[5] * invr),
                             msk[6] * __expf(e[6] * invr), msk[7] * __expf(e[7] * invr));
            ca[4] += o1.x; ca[5] += o1.y; ca[6] += o1.z; ca[7] += o1.w;
        }
        *(float4*)(Xb + (size_t)r * NM + m0) = o0;
        *(float4*)(Xb + (size_t)r * NM + m1) = o1;
    }
    const float4 z4 = make_float4(0.f, 0.f, 0.f, 0.f);
    for (; r < NN; r += 32) { // zero-fill invalid rows once
        *(float4*)(Xb + (size_t)r * NM + m0) = z4;
        *(float4*)(Xb + (size_t)r * NM + m1) = z4;
    }

    *(float4*)&red[wv][m0] = make_float4(ca[0], ca[1], ca[2], ca[3]);
    *(float4*)&red[wv][m1] = make_float4(ca[4], ca[5], ca[6], ca[7]);
    __syncthreads();
    {
        float* pb = part0 + (size_t)b * NM * STRIPS;
        const int c = tid * 2;
        pb[(size_t)c * STRIPS + s]       = (red[0][c] + red[1][c]) + (red[2][c] + red[3][c]);
        pb[(size_t)(c + 1) * STRIPS + s] = (red[0][c + 1] + red[1][c + 1]) + (red[2][c + 1] + red[3][c + 1]);
    }
}

__global__ __launch_bounds__(NTHREADS, 4)
void k1_cr(const int* __restrict__ nfree, const int* __restrict__ ntask,
           float* __restrict__ X, const float* __restrict__ ps,
           float* __restrict__ pd)
{
    const int b = blockIdx.x & (NB - 1);
    const int s = blockIdx.x >> 7;
    const int na = nfree[b], nt = ntask[b];
    const int tid = threadIdx.x, wv = tid >> 6, lane = tid & 63;
    float* __restrict__ Xb = X + (size_t)b * NN * NM;

    __shared__ __align__(16) float red[4][NM];
    __shared__ __align__(16) float csh[NM];

    const float* psb = ps + (size_t)b * NM * STRIPS;
    { // gather column sums from the 8 strip partials (L2-resident)
        const int c = tid * 2;
        const float4* p0 = (const float4*)(psb + (size_t)c * STRIPS);
        float4 u = p0[0], v = p0[1];
        csh[c] = ((u.x + u.y) + (u.z + u.w)) + ((v.x + v.y) + (v.z + v.w));
        const float4* p1 = (const float4*)(psb + (size_t)(c + 1) * STRIPS);
        u = p1[0]; v = p1[1];
        csh[c + 1] = ((u.x + u.y) + (u.z + u.w)) + ((v.x + v.y) + (v.z + v.w));
    }
    __syncthreads();

    const int m0 = lane * 4, m1 = 256 + lane * 4;
    const bool a0 = (m0 < nt), a1 = (m1 < nt);
    float msk[8], inv[8];
#pragma unroll
    for (int k = 0; k < 8; ++k) {
        const int m = (k < 4) ? m0 + k : m1 + k - 4;
        msk[k] = (m < nt) ? 1.f : 0.f;
        inv[k] = (m < nt) ? 1.0f / csh[m] : 0.f;
    }
    const int rstart = s + 8 * wv;
    float cn[8];
#pragma unroll
    for (int k = 0; k < 8; ++k) cn[k] = 0.f;

    for (int r = rstart; r < na; r += 32) {
        float ez[8];
#pragma unroll
        for (int k = 0; k < 8; ++k) ez[k] = 0.f;
        if (a0) {
            const float4 y = *(const float4*)(Xb + (size_t)r * NM + m0);
            ez[0] = msk[0] * __expf(y.x * inv[0]); ez[1] = msk[1] * __expf(y.y * inv[1]);
            ez[2] = msk[2] * __expf(y.z * inv[2]); ez[3] = msk[3] * __expf(y.w * inv[3]);
        }
        if (a1) {
            const float4 y = *(const float4*)(Xb + (size_t)r * NM + m1);
            ez[4] = msk[4] * __expf(y.x * inv[4]); ez[5] = msk[5] * __expf(y.y * inv[5]);
            ez[6] = msk[6] * __expf(y.z * inv[6]); ez[7] = msk[7] * __expf(y.w * inv[7]);
        }
        const float sum = wave_sum(((ez[0] + ez[1]) + (ez[2] + ez[3])) +
                                   ((ez[4] + ez[5]) + (ez[6] + ez[7])));
        const float invr = 1.0f / sum;
        if (a0) {
            const float4 o = make_float4(
                msk[0] * __expf(ez[0] * invr), msk[1] * __expf(ez[1] * invr),
                msk[2] * __expf(ez[2] * invr), msk[3] * __expf(ez[3] * invr));
            *(float4*)(Xb + (size_t)r * NM + m0) = o;
            cn[0] += o.x; cn[1] += o.y; cn[2] += o.z; cn[3] += o.w;
        }
        if (a1) {
            const float4 o = make_float4(
                msk[4] * __expf(ez[4] * invr), msk[5] * __expf(ez[5] * invr),
                msk[6] * __expf(ez[6] * invr), msk[7] * __expf(ez[7] * invr));
            *(float4*)(Xb + (size_t)r * NM + m1) = o;
            cn[4] += o.x; cn[5] += o.y; cn[6] += o.z; cn[7] += o.w;
        }
    }

    *(float4*)&red[wv][m0] = make_float4(cn[0], cn[1], cn[2], cn[3]);
    *(float4*)&red[wv][m1] = make_float4(cn[4], cn[5], cn[6], cn[7]);
    __syncthreads();
    {
        float* pdb = pd + (size_t)b * NM * STRIPS;
        const int c = tid * 2;
        pdb[(size_t)c * STRIPS + s]       = (red[0][c] + red[1][c]) + (red[2][c] + red[3][c]);
        pdb[(size_t)(c + 1) * STRIPS + s] = (red[0][c + 1] + red[1][c + 1]) + (red[2][c + 1] + red[3][c + 1]);
    }
}

__global__ __launch_bounds__(NTHREADS, 4)
void k2_fin(const int* __restrict__ nfree, const int* __restrict__ ntask,
            float* __restrict__ X, const float* __restrict__ ps)
{
    const int b = blockIdx.x & (NB - 1);
    const int s = blockIdx.x >> 7;
    const int na = nfree[b], nt = ntask[b];
    const int tid = threadIdx.x, wv = tid >> 6, lane = tid & 63;
    float* __restrict__ Xb = X + (size_t)b * NN * NM;

    __shared__ __align__(16) float csh[NM];
    const float* psb = ps + (size_t)b * NM * STRIPS;
    {
        const int c = tid * 2;
        const float4* p0 = (const float4*)(psb + (size_t)c * STRIPS);
        float4 u = p0[0], v = p0[1];
        csh[c] = ((u.x + u.y) + (u.z + u.w)) + ((v.x + v.y) + (v.z + v.w));
        const float4* p1 = (const float4*)(psb + (size_t)(c + 1) * STRIPS);
        u = p1[0]; v = p1[1];
        csh[c + 1] = ((u.x + u.y) + (u.z + u.w)) + ((v.x + v.y) + (v.z + v.w));
    }
    __syncthreads();

    const int m0 = lane * 4, m1 = 256 + lane * 4;
    const bool a0 = (m0 < nt), a1 = (m1 < nt);
    float inv[8];
#pragma unroll
    for (int k = 0; k < 8; ++k) {
        const int m = (k < 4) ? m0 + k : m1 + k - 4;
        inv[k] = (m < nt) ? 1.0f / csh[m] : 0.f;
    }
    const int rstart = s + 8 * wv;
    for (int r = rstart; r < na; r += 32) {
        if (a0) {
            const float4 y = *(const float4*)(Xb + (size_t)r * NM + m0);
            *(float4*)(Xb + (size_t)r * NM + m0) =
                make_float4(y.x * inv[0], y.y * inv[1], y.z * inv[2], y.w * inv[3]);
        }
        if (a1) {
            const float4 y = *(const float4*)(Xb + (size_t)r * NM + m1);
            *(float4*)(Xb + (size_t)r * NM + m1) =
                make_float4(y.x * inv[4], y.y * inv[5], y.z * inv[6], y.w * inv[7]);
        }
    }
}

extern "C" void kernel_launch(void* const* d_in, const int* in_sizes, int n_in,
                              void* d_out, int out_size, void* d_ws, size_t ws_size,
                              hipStream_t stream)
{
    (void)in_sizes; (void)n_in; (void)out_size; (void)ws_size;
    const float* logits = (const float*)d_in[0];
    const int* nfree    = (const int*)d_in[1];
    const int* ntask    = (const int*)d_in[2];
    float* X  = (float*)d_out;
    float* p0 = (float*)d_ws;       // [NB][NM][STRIPS] partial colsums, buffer 0
    float* p1 = p0 + PSZ;           // buffer 1 (total 4 MB of ws)

    const dim3 grid(NB * STRIPS), block(NTHREADS);
    hipLaunchKernelGGL(k0_init, grid, block, 0, stream, logits, nfree, ntask, X, p0);
    const float* src = p0;
    float* dst = p1;
    for (int it = 0; it < NITER - 1; ++it) {
        hipLaunchKernelGGL(k1_cr, grid, block, 0, stream, nfree, ntask, X, src, dst);
        const float* t = src; src = dst; dst = (float*)t;
    }
    hipLaunchKernelGGL(k2_fin, grid, block, 0, stream, nfree, ntask, X, src);
}